// Round 12
// baseline (49.540 us; speedup 1.0000x reference)
//
#include <hip/hip_runtime.h>

// Problem constants (fixed by setup_inputs): B=4, S=256, D=512, P=256
constexpr int B = 4;
constexpr int S = 256;
constexpr int D = 512;
constexpr int P = 256;
constexpr float NEG_INF = -1e9f;
constexpr float LOG2E = 1.4426950408889634f;
constexpr float C2 = 2.885390081777927f; // 2*log2(e): exp2(C2*x) = e^{2x}

__device__ __forceinline__ float fast_exp2(float x) {
#if __has_builtin(__builtin_amdgcn_exp2f)
    return __builtin_amdgcn_exp2f(x);
#else
    return exp2f(x);
#endif
}

__device__ __forceinline__ float fast_rcp(float x) {
#if __has_builtin(__builtin_amdgcn_rcpf)
    return __builtin_amdgcn_rcpf(x);
#else
    return 1.0f / x;
#endif
}

// ---------------------------------------------------------------------------
// proj v10: 32m x 64n tile, K-tile 64, **512 threads** (thread-tile 1m x 4n),
// 256 blocks, reg prefetch, exp2 epilogue. 2 waves/SIMD (was 1) hides the
// LDS/sched stalls that capped the 256-thread v5 at ~12us true.
//   bid < 128 : Eq[b*S+i][p]   bid >= 128 : EkT[b][p][j]
// ---------------------------------------------------------------------------
__global__ __launch_bounds__(512)
void proj_kernel(const float* __restrict__ seq,
                 const float* __restrict__ W1, const float* __restrict__ W2,
                 float* __restrict__ Eq, float* __restrict__ EkT) {
    __shared__ float As[64][34]; // [k][m]
    __shared__ float Ws[64][68]; // [k][n]

    int bid0 = blockIdx.x;
    int bid = (bid0 & 7) * 32 + (bid0 >> 3); // XCD swizzle (256 = 8*32)

    const float* A;
    const float* Bp;
    float* out;
    if (bid < 128) { // Eq
        int mt = bid >> 2, nt = bid & 3;
        A = seq + (size_t)mt * 32 * D;
        Bp = W2 + (size_t)nt * 64 * D;
        out = Eq + (size_t)mt * 32 * 256 + nt * 64;
    } else {         // EkT
        int r = bid - 128;
        int b = r >> 5, t = r & 31;
        int mt = t >> 2, nt = t & 3;
        A = W1 + (size_t)mt * 32 * D;
        Bp = seq + ((size_t)b * S + nt * 64) * D;
        out = EkT + (size_t)b * P * S + (size_t)mt * 32 * 256 + nt * 64;
    }

    int tid = threadIdx.x;
    int tx = tid & 15, ty = tid >> 4;     // compute: n-quad, m-row (0..31)
    int ar = tid >> 4, akc = tid & 15;    // A stage: row 0..31, 4-float chunk
    int br = tid >> 3, bkc = tid & 7;     // W stage: row 0..63, 8-float chunk
    const float* aptr = A + (size_t)ar * D + akc * 4;
    const float* bptr = Bp + (size_t)br * D + bkc * 8;

    float4 a0, w0, w1;
    a0 = *(const float4*)(aptr);
    w0 = *(const float4*)(bptr);
    w1 = *(const float4*)(bptr + 4);

    float c0[4] = {0.f, 0.f, 0.f, 0.f};

    for (int kt = 0; kt < 8; kt++) {
        int ka = akc * 4;
        As[ka + 0][ar] = a0.x; As[ka + 1][ar] = a0.y;
        As[ka + 2][ar] = a0.z; As[ka + 3][ar] = a0.w;
        int kb = bkc * 8;
        Ws[kb + 0][br] = w0.x; Ws[kb + 1][br] = w0.y;
        Ws[kb + 2][br] = w0.z; Ws[kb + 3][br] = w0.w;
        Ws[kb + 4][br] = w1.x; Ws[kb + 5][br] = w1.y;
        Ws[kb + 6][br] = w1.z; Ws[kb + 7][br] = w1.w;
        __syncthreads();
        if (kt < 7) { // prefetch next K-tile
            const float* ap = aptr + (kt + 1) * 64;
            const float* bp = bptr + (kt + 1) * 64;
            a0 = *(const float4*)(ap);
            w0 = *(const float4*)(bp);
            w1 = *(const float4*)(bp + 4);
        }
#pragma unroll 8
        for (int k = 0; k < 64; k++) {
            float av = As[k][ty];
            float4 wv = *(const float4*)&Ws[k][tx * 4];
            c0[0] = fmaf(av, wv.x, c0[0]);
            c0[1] = fmaf(av, wv.y, c0[1]);
            c0[2] = fmaf(av, wv.z, c0[2]);
            c0[3] = fmaf(av, wv.w, c0[3]);
        }
        __syncthreads();
    }
    float4 o0 = {fast_exp2(c0[0] * C2), fast_exp2(c0[1] * C2),
                 fast_exp2(c0[2] * C2), fast_exp2(c0[3] * C2)};
    *(float4*)&out[(size_t)ty * 256 + tx * 4] = o0;
}

// ---------------------------------------------------------------------------
// score_attn v10: block = (b, 4 queries), 512 threads, 256 blocks.
// Phase 1 (barrier-free, v8-pattern): thread = (j, p-half h); per p-step one
//   j-coalesced global b32 EkT load + one b128 Eqs[p][q] broadcast + 4 rcp
//   chains. score(i,j) = const + sum_p (-2 v[p]) * rcp(Eq[i,p]*EkT[p][j]+1).
// Phase 2: softmax (threads 0..255 = j) -> wsm (LDS) + wout (global).
// Phase 3: attn from LDS wsm: thread = d (512 = D), coalesced seq loads.
// One launch replaces score+attn (saves a dispatch gap + wout L2 round-trip).
// ---------------------------------------------------------------------------
__global__ __launch_bounds__(512)
void score_attn_kernel(const float* __restrict__ seq,
                       const float* __restrict__ EkT, const float* __restrict__ Eq,
                       const float* __restrict__ v, const float* __restrict__ mask,
                       float* __restrict__ wout, float* __restrict__ attn) {
    __shared__ float Eqs[P][4];      // 4 KB [p][q]
    __shared__ float vsm[P];         // 1 KB (-2v)
    __shared__ float part[2][S][4];  // 8 KB [h][j][q]
    __shared__ float wsm[S][4];      // 4 KB [j][q]
    __shared__ float redm[4][4], reds[4][4];

    int bid0 = blockIdx.x;
    int bid = (bid0 & 7) * 32 + (bid0 >> 3); // XCD swizzle (256 = 8*32)
    int b = bid >> 6;
    int i0 = (bid & 63) * 4;
    int tid = threadIdx.x;

    // stage Eqs[p][q] (transposed gather) and v' = -2v
    if (tid < 256) {
        int p = tid;
        float e0 = Eq[((size_t)b * S + i0 + 0) * P + p];
        float e1 = Eq[((size_t)b * S + i0 + 1) * P + p];
        float e2 = Eq[((size_t)b * S + i0 + 2) * P + p];
        float e3 = Eq[((size_t)b * S + i0 + 3) * P + p];
        *(float4*)&Eqs[p][0] = make_float4(e0, e1, e2, e3);
        vsm[p] = -2.f * v[p];
    }
    __syncthreads();

    // phase 1: barrier-free; thread = (j, h); 128 p-steps
    int j = tid & 255, h = tid >> 8;
    {
        const float* ekp = EkT + ((size_t)b * P + h * 128) * S + j;
        float a0 = 0.f, a1 = 0.f, a2 = 0.f, a3 = 0.f;
#pragma unroll 8
        for (int pp = 0; pp < 128; ++pp) {
            float ek = ekp[(size_t)pp * S];
            int p = h * 128 + pp;
            float4 eq = *(const float4*)&Eqs[p][0];
            float vv = vsm[p];
            a0 = fmaf(vv, fast_rcp(fmaf(ek, eq.x, 1.f)), a0);
            a1 = fmaf(vv, fast_rcp(fmaf(ek, eq.y, 1.f)), a1);
            a2 = fmaf(vv, fast_rcp(fmaf(ek, eq.z, 1.f)), a2);
            a3 = fmaf(vv, fast_rcp(fmaf(ek, eq.w, 1.f)), a3);
        }
        *(float4*)&part[h][j][0] = make_float4(a0, a1, a2, a3);
    }
    __syncthreads();

    // phase 2: softmax over keys (threads 0..255 = j)
    int lane = tid & 63, wid = tid >> 6; // wid 0..3 for tid<256
    float s[4], e[4] = {0.f, 0.f, 0.f, 0.f};
    if (tid < 256) {
        float km = mask[(size_t)b * S + j];
        float4 p0 = *(const float4*)&part[0][j][0];
        float4 p1 = *(const float4*)&part[1][j][0];
        s[0] = p0.x + p1.x; s[1] = p0.y + p1.y;
        s[2] = p0.z + p1.z; s[3] = p0.w + p1.w;
        if (!(km > 0.f)) { s[0] = NEG_INF; s[1] = NEG_INF;
                           s[2] = NEG_INF; s[3] = NEG_INF; }
#pragma unroll
        for (int q = 0; q < 4; q++) {
            float mm = s[q];
#pragma unroll
            for (int off = 32; off >= 1; off >>= 1)
                mm = fmaxf(mm, __shfl_xor(mm, off, 64));
            if (lane == 0) redm[q][wid] = mm;
        }
    }
    __syncthreads();
    if (tid < 256) {
#pragma unroll
        for (int q = 0; q < 4; q++) {
            float mm = fmaxf(fmaxf(redm[q][0], redm[q][1]),
                             fmaxf(redm[q][2], redm[q][3]));
            float ee = fast_exp2((s[q] - mm) * LOG2E);
            e[q] = ee;
            float ss = ee;
#pragma unroll
            for (int off = 32; off >= 1; off >>= 1)
                ss += __shfl_xor(ss, off, 64);
            if (lane == 0) reds[q][wid] = ss;
        }
    }
    __syncthreads();
    if (tid < 256) {
        float w4[4];
#pragma unroll
        for (int q = 0; q < 4; q++) {
            float ssum = (reds[q][0] + reds[q][1]) + (reds[q][2] + reds[q][3]);
            float qm = mask[(size_t)b * S + i0 + q];
            w4[q] = e[q] * fast_rcp(ssum) * qm;
            wout[((size_t)b * S + i0 + q) * S + j] = w4[q];
        }
        *(float4*)&wsm[j][0] = make_float4(w4[0], w4[1], w4[2], w4[3]);
    }
    __syncthreads();

    // phase 3: attn[b, i0+q, d] = sum_j wsm[j][q] * seq[b, j, d]; thread = d
    {
        int d = tid;
        const float* sp = seq + (size_t)b * S * D + d;
        float A0 = 0.f, A1 = 0.f, A2 = 0.f, A3 = 0.f;
#pragma unroll 8
        for (int jj = 0; jj < S; ++jj) {
            float sv = sp[(size_t)jj * D];
            float4 wv = *(const float4*)&wsm[jj][0];
            A0 = fmaf(wv.x, sv, A0);
            A1 = fmaf(wv.y, sv, A1);
            A2 = fmaf(wv.z, sv, A2);
            A3 = fmaf(wv.w, sv, A3);
        }
        attn[((size_t)b * S + i0 + 0) * D + d] = A0;
        attn[((size_t)b * S + i0 + 1) * D + d] = A1;
        attn[((size_t)b * S + i0 + 2) * D + d] = A2;
        attn[((size_t)b * S + i0 + 3) * D + d] = A3;
    }
}

// ---------------------------------------------------------------------------
extern "C" void kernel_launch(void* const* d_in, const int* in_sizes, int n_in,
                              void* d_out, int out_size, void* d_ws, size_t ws_size,
                              hipStream_t stream) {
    const float* seq  = (const float*)d_in[0];
    const float* mask = (const float*)d_in[1];
    const float* W1   = (const float*)d_in[2];
    const float* W2   = (const float*)d_in[3];
    const float* v    = (const float*)d_in[4];

    float* attn = (float*)d_out;                 // [B,S,D]
    float* wout = attn + (size_t)B * S * D;      // [B,S,S]

    float* Eq  = (float*)d_ws;                   // [B*S, P]  = exp2(C2*pq)
    float* EkT = Eq + (size_t)B * S * P;         // [B, P, S] = exp2(C2*pk)^T

    proj_kernel<<<256, 512, 0, stream>>>(seq, W1, W2, Eq, EkT);
    score_attn_kernel<<<256, 512, 0, stream>>>(seq, EkT, Eq, v, mask,
                                               wout, attn);
}

// Round 13
// 46.790 us; speedup vs baseline: 1.0588x; 1.0588x over previous
//
#include <hip/hip_runtime.h>

// Problem constants (fixed by setup_inputs): B=4, S=256, D=512, P=256
constexpr int B = 4;
constexpr int S = 256;
constexpr int D = 512;
constexpr int P = 256;
constexpr float NEG_INF = -1e9f;
constexpr float LOG2E = 1.4426950408889634f;
constexpr float C2 = 2.885390081777927f; // 2*log2(e):  exp2(C2*x) = e^{2x}

__device__ __forceinline__ float fast_exp2(float x) {
#if __has_builtin(__builtin_amdgcn_exp2f)
    return __builtin_amdgcn_exp2f(x);
#else
    return exp2f(x);
#endif
}

__device__ __forceinline__ float fast_rcp(float x) {
#if __has_builtin(__builtin_amdgcn_rcpf)
    return __builtin_amdgcn_rcpf(x);
#else
    return 1.0f / x;
#endif
}

// ---------------------------------------------------------------------------
// proj v11: 32m x 64n tile, K-tile 64, **512 threads, thread-tile 2m x 2n**,
// 256 blocks, reg prefetch, exp2 epilogue. 2 waves/SIMD (v5 had 1) to hide
// ds_read->fma latency; per k-step 2x b64 LDS + 4 fma (VALU-leaning).
//   bid < 128 : Eq[b*S+i][p]   bid >= 128 : EkT[b][p][j]
// ---------------------------------------------------------------------------
__global__ __launch_bounds__(512)
void proj_kernel(const float* __restrict__ seq,
                 const float* __restrict__ W1, const float* __restrict__ W2,
                 float* __restrict__ Eq, float* __restrict__ EkT) {
    __shared__ float As[64][34]; // [k][m]
    __shared__ float Ws[64][67]; // [k][n]

    int bid0 = blockIdx.x;
    int bid = (bid0 & 7) * 32 + (bid0 >> 3); // XCD swizzle (256 = 8*32)

    const float* A;
    const float* Bp;
    float* out;
    if (bid < 128) { // Eq
        int mt = bid >> 2, nt = bid & 3;
        A = seq + (size_t)mt * 32 * D;
        Bp = W2 + (size_t)nt * 64 * D;
        out = Eq + (size_t)mt * 32 * 256 + nt * 64;
    } else {         // EkT
        int r = bid - 128;
        int b = r >> 5, t = r & 31;
        int mt = t >> 2, nt = t & 3;
        A = W1 + (size_t)mt * 32 * D;
        Bp = seq + ((size_t)b * S + nt * 64) * D;
        out = EkT + (size_t)b * P * S + (size_t)mt * 32 * 256 + nt * 64;
    }

    int tid = threadIdx.x;
    int tx = tid & 31, ty = tid >> 5;    // compute: n-pair (0..31), m-pair (0..15)
    int ar = tid >> 4, akc = tid & 15;   // A stage: row 0..31, 4-float chunk
    int br = tid >> 3, bkc = tid & 7;    // W stage: row 0..63, 8-float chunk
    const float* aptr = A + (size_t)ar * D + akc * 4;
    const float* bptr = Bp + (size_t)br * D + bkc * 8;

    float4 a0, w0, w1;
    a0 = *(const float4*)(aptr);
    w0 = *(const float4*)(bptr);
    w1 = *(const float4*)(bptr + 4);

    float c00 = 0.f, c01 = 0.f, c10 = 0.f, c11 = 0.f;

    for (int kt = 0; kt < 8; kt++) {
        int ka = akc * 4;
        As[ka + 0][ar] = a0.x; As[ka + 1][ar] = a0.y;
        As[ka + 2][ar] = a0.z; As[ka + 3][ar] = a0.w;
        int kb = bkc * 8;
        Ws[kb + 0][br] = w0.x; Ws[kb + 1][br] = w0.y;
        Ws[kb + 2][br] = w0.z; Ws[kb + 3][br] = w0.w;
        Ws[kb + 4][br] = w1.x; Ws[kb + 5][br] = w1.y;
        Ws[kb + 6][br] = w1.z; Ws[kb + 7][br] = w1.w;
        __syncthreads();
        if (kt < 7) { // prefetch next K-tile while computing this one
            const float* ap = aptr + (kt + 1) * 64;
            const float* bp = bptr + (kt + 1) * 64;
            a0 = *(const float4*)(ap);
            w0 = *(const float4*)(bp);
            w1 = *(const float4*)(bp + 4);
        }
#pragma unroll 8
        for (int k = 0; k < 64; k++) {
            float2 av = *(const float2*)&As[k][ty * 2];
            float2 wv = *(const float2*)&Ws[k][tx * 2];
            c00 = fmaf(av.x, wv.x, c00);
            c01 = fmaf(av.x, wv.y, c01);
            c10 = fmaf(av.y, wv.x, c10);
            c11 = fmaf(av.y, wv.y, c11);
        }
        __syncthreads();
    }
    float2 o0 = {fast_exp2(c00 * C2), fast_exp2(c01 * C2)};
    float2 o1 = {fast_exp2(c10 * C2), fast_exp2(c11 * C2)};
    *(float2*)&out[(size_t)(ty * 2 + 0) * 256 + tx * 2] = o0;
    *(float2*)&out[(size_t)(ty * 2 + 1) * 256 + tx * 2] = o1;
}

// ---------------------------------------------------------------------------
// score_attn v5 (EXACT copy of R5's kernel — measured 25.2us in-graph).
// ---------------------------------------------------------------------------
__global__ __launch_bounds__(512)
void score_attn_kernel(const float* __restrict__ seq,
                       const float* __restrict__ EkT, const float* __restrict__ Eq,
                       const float* __restrict__ v, const float* __restrict__ mask,
                       float* __restrict__ wout, float* __restrict__ attn) {
    __shared__ float Eqs[4][P];        // 4 KB
    __shared__ float vsm[P];           // 1 KB  (-2*v)
    __shared__ float ekb[2][32][256];  // 64 KB double-buffered Ek chunks
    __shared__ float part[2][4][S];    // 8 KB  [h][q][j]
    __shared__ float wsm[S][4];        // 4 KB
    __shared__ float p3[4][4][D];      // 32 KB [jh][q][d]
    __shared__ float redm[4][8], reds[4][8];

    int bid0 = blockIdx.x;
    int bid = (bid0 & 7) * 32 + (bid0 >> 3); // XCD swizzle (256 = 8*32)
    int b = bid >> 6;
    int i0 = (bid & 63) * 4;
    int tid = threadIdx.x;
    int lane = tid & 63, wid = tid >> 6;

    const float* ekbase = EkT + (size_t)b * P * S; // 65536 floats, chunk = 8192

    float4 r0, r1, r2, r3;
#define LOADC(c)                                                       \
    {                                                                  \
        const float4* sp_ = (const float4*)(ekbase + (c) * 8192);      \
        r0 = sp_[tid]; r1 = sp_[tid + 512];                            \
        r2 = sp_[tid + 1024]; r3 = sp_[tid + 1536];                    \
    }
#define WRITEC(bf)                                                     \
    {                                                                  \
        float4* dp_ = (float4*)&ekb[bf][0][0];                         \
        dp_[tid] = r0; dp_[tid + 512] = r1;                            \
        dp_[tid + 1024] = r2; dp_[tid + 1536] = r3;                    \
    }

    LOADC(0);
    // stage Eq rows (4 x 256 contiguous) and v' = -2v
    ((float2*)Eqs)[tid] = ((const float2*)(Eq + ((size_t)b * S + i0) * P))[tid];
    if (tid < 128) {
        float2 vv = ((const float2*)v)[tid];
        ((float2*)vsm)[tid] = make_float2(-2.f * vv.x, -2.f * vv.y);
    }
    WRITEC(0);
    LOADC(1);
    __syncthreads();

    // phase 1
    int j = tid & 255, h = tid >> 8;
    float acc[4] = {0.f, 0.f, 0.f, 0.f};
    for (int c = 0; c < 8; c++) {
        int cur = c & 1;
        int pl0 = h * 16;
        int pg0 = c * 32 + pl0;
#pragma unroll
        for (int t = 0; t < 4; t++) {
            int pl = pl0 + t * 4, pg = pg0 + t * 4;
            float e0 = ekb[cur][pl + 0][j];
            float e1 = ekb[cur][pl + 1][j];
            float e2 = ekb[cur][pl + 2][j];
            float e3 = ekb[cur][pl + 3][j];
            float4 vv = *(const float4*)&vsm[pg];
#pragma unroll
            for (int q = 0; q < 4; q++) {
                float4 eq = *(const float4*)&Eqs[q][pg];
                acc[q] = fmaf(vv.x, fast_rcp(fmaf(e0, eq.x, 1.f)), acc[q]);
                acc[q] = fmaf(vv.y, fast_rcp(fmaf(e1, eq.y, 1.f)), acc[q]);
                acc[q] = fmaf(vv.z, fast_rcp(fmaf(e2, eq.z, 1.f)), acc[q]);
                acc[q] = fmaf(vv.w, fast_rcp(fmaf(e3, eq.w, 1.f)), acc[q]);
            }
        }
        if (c < 7) { WRITEC(cur ^ 1); }
        if (c < 6) { LOADC(c + 2); }
        __syncthreads();
    }
#undef LOADC
#undef WRITEC
#pragma unroll
    for (int q = 0; q < 4; q++) part[h][q][j] = acc[q];
    __syncthreads();

    // phase 2: softmax over keys (threads 0..255 = j)
    float s[4], e[4] = {0.f, 0.f, 0.f, 0.f};
    if (tid < 256) {
        float km = mask[(size_t)b * S + j];
#pragma unroll
        for (int q = 0; q < 4; q++) {
            float sv = part[0][q][j] + part[1][q][j];
            s[q] = (km > 0.f) ? sv : NEG_INF;
            float mm = s[q];
#pragma unroll
            for (int off = 32; off >= 1; off >>= 1)
                mm = fmaxf(mm, __shfl_xor(mm, off, 64));
            if (lane == 0) redm[q][wid] = mm;
        }
    }
    __syncthreads();
    if (tid < 256) {
#pragma unroll
        for (int q = 0; q < 4; q++) {
            float mm = fmaxf(fmaxf(redm[q][0], redm[q][1]),
                             fmaxf(redm[q][2], redm[q][3]));
            float ee = fast_exp2((s[q] - mm) * LOG2E);
            e[q] = ee;
            float ss = ee;
#pragma unroll
            for (int off = 32; off >= 1; off >>= 1)
                ss += __shfl_xor(ss, off, 64);
            if (lane == 0) reds[q][wid] = ss;
        }
    }
    __syncthreads();
    if (tid < 256) {
#pragma unroll
        for (int q = 0; q < 4; q++) {
            float ssum = (reds[q][0] + reds[q][1]) + (reds[q][2] + reds[q][3]);
            float qm = mask[(size_t)b * S + i0 + q];
            float w = e[q] * fast_rcp(ssum) * qm;
            wsm[j][q] = w;
            wout[((size_t)b * S + i0 + q) * S + j] = w;
        }
    }
    __syncthreads();

    // phase 3: attn = w @ seq. thread = (dg -> 4 d, jh -> 64 j), float4 loads.
    {
        int dg = tid & 127, jh = tid >> 7;
        int d0 = dg * 4;
        const float4* sp = (const float4*)(seq + (size_t)b * S * D);
        float4 A0 = {0.f, 0.f, 0.f, 0.f}, A1 = {0.f, 0.f, 0.f, 0.f};
        float4 A2 = {0.f, 0.f, 0.f, 0.f}, A3 = {0.f, 0.f, 0.f, 0.f};
#pragma unroll 4
        for (int jj = 0; jj < 64; jj++) {
            int jx = jh * 64 + jj;
            float4 s4 = sp[(size_t)jx * 128 + dg];
            float4 w4 = *(const float4*)&wsm[jx][0];
            A0.x = fmaf(w4.x, s4.x, A0.x); A0.y = fmaf(w4.x, s4.y, A0.y);
            A0.z = fmaf(w4.x, s4.z, A0.z); A0.w = fmaf(w4.x, s4.w, A0.w);
            A1.x = fmaf(w4.y, s4.x, A1.x); A1.y = fmaf(w4.y, s4.y, A1.y);
            A1.z = fmaf(w4.y, s4.z, A1.z); A1.w = fmaf(w4.y, s4.w, A1.w);
            A2.x = fmaf(w4.z, s4.x, A2.x); A2.y = fmaf(w4.z, s4.y, A2.y);
            A2.z = fmaf(w4.z, s4.z, A2.z); A2.w = fmaf(w4.z, s4.w, A2.w);
            A3.x = fmaf(w4.w, s4.x, A3.x); A3.y = fmaf(w4.w, s4.y, A3.y);
            A3.z = fmaf(w4.w, s4.z, A3.z); A3.w = fmaf(w4.w, s4.w, A3.w);
        }
        *(float4*)&p3[jh][0][d0] = A0;
        *(float4*)&p3[jh][1][d0] = A1;
        *(float4*)&p3[jh][2][d0] = A2;
        *(float4*)&p3[jh][3][d0] = A3;
    }
    __syncthreads();
    {
        int d = tid;
#pragma unroll
        for (int q = 0; q < 4; q++) {
            float r = (p3[0][q][d] + p3[1][q][d]) + (p3[2][q][d] + p3[3][q][d]);
            attn[((size_t)b * S + i0 + q) * D + d] = r;
        }
    }
}

// ---------------------------------------------------------------------------
extern "C" void kernel_launch(void* const* d_in, const int* in_sizes, int n_in,
                              void* d_out, int out_size, void* d_ws, size_t ws_size,
                              hipStream_t stream) {
    const float* seq  = (const float*)d_in[0];
    const float* mask = (const float*)d_in[1];
    const float* W1   = (const float*)d_in[2];
    const float* W2   = (const float*)d_in[3];
    const float* v    = (const float*)d_in[4];

    float* attn = (float*)d_out;                 // [B,S,D]
    float* wout = attn + (size_t)B * S * D;      // [B,S,S]

    float* Eq  = (float*)d_ws;                   // [B*S, P]  = exp2(C2*pq)
    float* EkT = Eq + (size_t)B * S * P;         // [B, P, S] = exp2(C2*pk)^T

    proj_kernel<<<256, 512, 0, stream>>>(seq, W1, W2, Eq, EkT);
    score_attn_kernel<<<256, 512, 0, stream>>>(seq, EkT, Eq, v, mask,
                                               wout, attn);
}